// Round 1
// 524.250 us; speedup vs baseline: 1.0168x; 1.0168x over previous
//
#include <hip/hip_runtime.h>
#include <hip/hip_bf16.h>

// Problem constants: B=32, T=1024, D=512, K=3, L=max_len=4096.
#define BB 32
#define TT 1024
#define DD 512
#define LL 4096
#define KDIM 1536        // K*D (im2col reduction dim)
#define TP 1026          // padded T (+1 zero halo row each side)
#define ROWS (BB * TT)   // 32768

typedef __attribute__((ext_vector_type(8))) short short8;
typedef __attribute__((ext_vector_type(8))) unsigned short ushort8;
typedef __attribute__((ext_vector_type(4))) float floatx4;

__device__ __forceinline__ unsigned short f2bf(float f) {
  unsigned int u = __builtin_bit_cast(unsigned int, f);
  u += 0x7FFF + ((u >> 16) & 1);
  return (unsigned short)(u >> 16);
}
__device__ __forceinline__ float bf2f(unsigned short h) {
  return __builtin_bit_cast(float, (unsigned int)h << 16);
}

#define GLOAD_LDS16(g, l)                                          \
  __builtin_amdgcn_global_load_lds(                                \
      (const __attribute__((address_space(1))) void*)(g),          \
      (__attribute__((address_space(3))) void*)(l), 16, 0, 0)

// ---------------------------------------------------------------------------
// enc fp32 -> bf16 padded [32][1026][512] (zero halos), PLUS zeroing the halo
// rows of h1_pad (blocks >= PAD_BLKS).
// ---------------------------------------------------------------------------
#define PAD_BLKS ((BB * TP) / 4)  // 8208
__global__ __launch_bounds__(256) void pad_convert_kernel(
    const float* __restrict__ X, unsigned short* __restrict__ Xp,
    unsigned short* __restrict__ Hp) {
  const int lane = threadIdx.x & 63;
  if (blockIdx.x >= PAD_BLKS) {
    const int hid = (blockIdx.x - PAD_BLKS) * 4 + (threadIdx.x >> 6);
    const int b = hid >> 1;
    const long r = (long)b * TP + ((hid & 1) ? (TP - 1) : 0);
    *reinterpret_cast<ushort8*>(Hp + r * DD + lane * 8) = (ushort8)0;
    return;
  }
  const int row = blockIdx.x * 4 + (threadIdx.x >> 6);
  const int b  = row / TP;
  const int pr = row - b * TP;
  ushort8* o = reinterpret_cast<ushort8*>(Xp + (long)row * DD + lane * 8);
  ushort8 v;
  if (pr == 0 || pr == TP - 1) {
    v = (ushort8)0;
  } else {
    const float* p = X + ((long)(b * TT + pr - 1)) * DD + lane * 8;
    float4 a = *reinterpret_cast<const float4*>(p);
    float4 c = *reinterpret_cast<const float4*>(p + 4);
    v[0] = f2bf(a.x); v[1] = f2bf(a.y); v[2] = f2bf(a.z); v[3] = f2bf(a.w);
    v[4] = f2bf(c.x); v[5] = f2bf(c.y); v[6] = f2bf(c.z); v[7] = f2bf(c.w);
  }
  *o = v;
}

// ---------------------------------------------------------------------------
// Both weights: W fp32 [1536][512] -> Wt bf16 [512][1536], LDS-tiled.
// ---------------------------------------------------------------------------
__global__ __launch_bounds__(256) void convert_wt_kernel(
    const float* __restrict__ W1, unsigned short* __restrict__ Wt1,
    const float* __restrict__ W2, unsigned short* __restrict__ Wt2) {
  __shared__ float tile[64][65];
  const float* W = (blockIdx.z == 0) ? W1 : W2;
  unsigned short* Wt = (blockIdx.z == 0) ? Wt1 : Wt2;
  const int n0 = blockIdx.x * 64;
  const int k0 = blockIdx.y * 64;
  const int c = threadIdx.x & 63;
  const int r4 = threadIdx.x >> 6;
#pragma unroll
  for (int r = 0; r < 16; ++r) tile[r * 4 + r4][c] = W[(long)(k0 + r * 4 + r4) * DD + n0 + c];
  __syncthreads();
#pragma unroll
  for (int r = 0; r < 16; ++r)
    Wt[(long)(n0 + r * 4 + r4) * KDIM + k0 + c] = f2bf(tile[c][r * 4 + r4]);
}

// ---------------------------------------------------------------------------
// Fused conv-as-GEMM + bias + ReLU + LayerNorm (+ linear head for LAYER==2).
// Tile: 128 rows x FULL N=512, so LN reduces entirely in-block (no partial
// stats round-trip, no separate ln_apply pass).
// 512 threads = 8 waves (2 M-halves x 4 N-quarters), each wave 64x128
// (acc[4][8]); BK=32; LDS double-buffered (87 KB) with min-2-phase prefetch:
// issue next tile's global_load_lds BEFORE ds_read+MFMA of current tile, one
// barrier per K-step, so the vmcnt drain at the barrier hits ~400-cycle-old
// loads. Grid = 256 blocks = 1/CU (LDS+VGPR bound); all blocks share the
// whole Wt (1.5 MB, L2-resident).
// XOR chunk swizzle (pre-swizzled global source + swizzled ds_read) keeps
// both staging and fragment reads bank-conflict-free — same proven pattern
// as the previous kernel.
// ---------------------------------------------------------------------------
template <int LAYER>
__global__ __launch_bounds__(512, 2) void fused_conv_ln_kernel(
    const unsigned short* __restrict__ Xp, const unsigned short* __restrict__ Wt,
    const float* __restrict__ bias, const float* __restrict__ g,
    const float* __restrict__ be, const float* __restrict__ lw,
    const float* __restrict__ lb, unsigned short* __restrict__ Hp,
    float* __restrict__ dpo) {
  __shared__ unsigned short As[2][128 * 32];  // 2 x 8 KB
  __shared__ unsigned short Bs[2][512 * 32];  // 2 x 32 KB
  __shared__ float sS[4][128];
  __shared__ float sQ[4][128];
  __shared__ float muL[128];
  __shared__ float rsL[128];

  const int tid  = threadIdx.x;
  const int lane = tid & 63;
  const int wid  = tid >> 6;           // 0..7
  const int srow = lane >> 2;          // staging row within 16
  const int gchunk = (lane & 3) ^ (srow & 3);
  const int frow = lane & 15;
  const int quad = lane >> 4;
  const int rdch = quad ^ (frow & 3);
  const int wm = (wid >> 2) * 64;      // M-half
  const int wn = (wid & 3) * 128;      // N-quarter
  const int wc = wid & 3;

  const int m0 = blockIdx.x * 128;     // 128-row tiles never cross a batch
  const int bA = m0 >> 10;
  const int t0 = m0 & (TT - 1);

  const unsigned short* gA0 =
      Xp + (long)(bA * TP + t0 + wid * 16 + srow) * DD + gchunk * 8;
  const unsigned short* gB0 =
      Wt + (long)(wid * 16 + srow) * KDIM + gchunk * 8;

  floatx4 acc[4][8];
#pragma unroll
  for (int i = 0; i < 4; ++i)
#pragma unroll
    for (int j = 0; j < 8; ++j) acc[i][j] = (floatx4){0.f, 0.f, 0.f, 0.f};

#define STAGE(bi, kk)                                                         \
  do {                                                                        \
    const int tap_ = (kk) >> 9;                                               \
    const int c0_  = (kk) & 511;                                              \
    GLOAD_LDS16(gA0 + (long)tap_ * DD + c0_, &As[bi][(wid * 16) * 32]);       \
    GLOAD_LDS16(gB0 + (kk),                   &Bs[bi][(wid * 16) * 32]);      \
    GLOAD_LDS16(gB0 + (long)128 * KDIM + (kk), &Bs[bi][(128 + wid * 16) * 32]); \
    GLOAD_LDS16(gB0 + (long)256 * KDIM + (kk), &Bs[bi][(256 + wid * 16) * 32]); \
    GLOAD_LDS16(gB0 + (long)384 * KDIM + (kk), &Bs[bi][(384 + wid * 16) * 32]); \
  } while (0)

  STAGE(0, 0);
  __syncthreads();
  int cur = 0;
  for (int k0 = 0; k0 < KDIM; k0 += 32) {
    if (k0 + 32 < KDIM) STAGE(cur ^ 1, k0 + 32);  // prefetch next tile
    short8 a_[4], b_[8];
#pragma unroll
    for (int i = 0; i < 4; ++i)
      a_[i] = *reinterpret_cast<const short8*>(
          &As[cur][(wm + i * 16 + frow) * 32 + rdch * 8]);
#pragma unroll
    for (int j = 0; j < 8; ++j)
      b_[j] = *reinterpret_cast<const short8*>(
          &Bs[cur][(wn + j * 16 + frow) * 32 + rdch * 8]);
#pragma unroll
    for (int i = 0; i < 4; ++i)
#pragma unroll
      for (int j = 0; j < 8; ++j)
        acc[i][j] = __builtin_amdgcn_mfma_f32_16x16x32_bf16(
            a_[i], b_[j], acc[i][j], 0, 0, 0);
    __syncthreads();  // drains prefetch vmcnt; next buffer ready
    cur ^= 1;
  }
#undef STAGE

  // --- bias + relu in place ---
  float bz[8];
#pragma unroll
  for (int j = 0; j < 8; ++j) bz[j] = bias[wn + j * 16 + frow];
#pragma unroll
  for (int i = 0; i < 4; ++i)
#pragma unroll
    for (int j = 0; j < 8; ++j)
#pragma unroll
      for (int r = 0; r < 4; ++r)
        acc[i][j][r] = fmaxf(acc[i][j][r] + bz[j], 0.f);

  // --- per-row LN stats: this wave's 128 cols -> shfl over frow -> LDS ---
  float ps[16], pq[16];
#pragma unroll
  for (int i = 0; i < 4; ++i)
#pragma unroll
    for (int r = 0; r < 4; ++r) {
      float s = 0.f, q = 0.f;
#pragma unroll
      for (int j = 0; j < 8; ++j) {
        const float v = acc[i][j][r];
        s += v; q += v * v;
      }
      ps[i * 4 + r] = s; pq[i * 4 + r] = q;
    }
#pragma unroll
  for (int off = 1; off < 16; off <<= 1)
#pragma unroll
    for (int k = 0; k < 16; ++k) {
      ps[k] += __shfl_xor(ps[k], off);
      pq[k] += __shfl_xor(pq[k], off);
    }
  if (frow == 0) {
#pragma unroll
    for (int i = 0; i < 4; ++i)
#pragma unroll
      for (int r = 0; r < 4; ++r) {
        const int row = wm + i * 16 + quad * 4 + r;
        sS[wc][row] = ps[i * 4 + r];
        sQ[wc][row] = pq[i * 4 + r];
      }
  }
  __syncthreads();
  if (tid < 128) {
    const float s = sS[0][tid] + sS[1][tid] + sS[2][tid] + sS[3][tid];
    const float q = sQ[0][tid] + sQ[1][tid] + sQ[2][tid] + sQ[3][tid];
    const float mu = s * (1.f / DD);
    const float var = q * (1.f / DD) - mu * mu;
    muL[tid] = mu;
    rsL[tid] = rsqrtf(var + 1e-5f);
  }
  __syncthreads();

  float gg[8], bb[8];
#pragma unroll
  for (int j = 0; j < 8; ++j) {
    gg[j] = g[wn + j * 16 + frow];
    bb[j] = be[wn + j * 16 + frow];
  }

  if constexpr (LAYER == 1) {
    // LN -> bf16 into padded h1 (row t+1).
#pragma unroll
    for (int i = 0; i < 4; ++i)
#pragma unroll
      for (int r = 0; r < 4; ++r) {
        const int row = wm + i * 16 + quad * 4 + r;
        const float mu = muL[row];
        const float rs = rsL[row];
        const long orow = (long)(bA * TP + t0 + row + 1) * DD;
#pragma unroll
        for (int j = 0; j < 8; ++j) {
          const float v = (acc[i][j][r] - mu) * rs * gg[j] + bb[j];
          Hp[orow + wn + j * 16 + frow] = f2bf(v);
        }
      }
  } else {
    // LN -> dot with lin_w -> dpo (tiny write, no Y materialization).
    float ww[8];
#pragma unroll
    for (int j = 0; j < 8; ++j) ww[j] = lw[wn + j * 16 + frow];
#pragma unroll
    for (int i = 0; i < 4; ++i)
#pragma unroll
      for (int r = 0; r < 4; ++r) {
        const int row = wm + i * 16 + quad * 4 + r;
        const float mu = muL[row];
        const float rs = rsL[row];
        float d = 0.f;
#pragma unroll
        for (int j = 0; j < 8; ++j) {
          const float v = (acc[i][j][r] - mu) * rs * gg[j] + bb[j];
          d += v * ww[j];
        }
#pragma unroll
        for (int off = 1; off < 16; off <<= 1) d += __shfl_xor(d, off);
        if (frow == 0) sS[wc][row] = d;  // reuse sS (all stat reads done)
      }
    __syncthreads();
    if (tid < 128)
      dpo[m0 + tid] =
          sS[0][tid] + sS[1][tid] + sS[2][tid] + sS[3][tid] + lb[0];
  }
}

// Inclusive cumsum over T=1024 per batch.
__global__ __launch_bounds__(1024) void cumsum_kernel(
    const int* __restrict__ dur, int* __restrict__ cum) {
  __shared__ int s[TT];
  const int b = blockIdx.x, t = threadIdx.x;
  s[t] = dur[b * TT + t];
  __syncthreads();
  for (int off = 1; off < TT; off <<= 1) {
    int x = (t >= off) ? s[t - off] : 0;
    __syncthreads();
    s[t] += x;
    __syncthreads();
  }
  cum[b * TT + t] = s[t];
}

// Gather/expand: one 128-thread block per output frame [b, j].
__global__ __launch_bounds__(128) void gather_kernel(
    const float* __restrict__ X, const int* __restrict__ cum,
    float* __restrict__ out) {
  const long blk = blockIdx.x;
  const int b = (int)(blk >> 12);
  const int j = (int)(blk & (LL - 1));
  const int* c = cum + b * TT;
  float4* o = reinterpret_cast<float4*>(out + blk * DD) + threadIdx.x;
  const int total = c[TT - 1];
  if (j >= total) {
    *o = make_float4(0.f, 0.f, 0.f, 0.f);
    return;
  }
  int lo = 0, hi = TT - 1;
  while (lo < hi) {
    const int mid = (lo + hi) >> 1;
    if (c[mid] <= j) lo = mid + 1; else hi = mid;
  }
  const float4* src =
      reinterpret_cast<const float4*>(X + ((long)b * TT + lo) * DD) +
      threadIdx.x;
  *o = *src;
}

// ---------------------------------------------------------------------------
extern "C" void kernel_launch(void* const* d_in, const int* in_sizes, int n_in,
                              void* d_out, int out_size, void* d_ws,
                              size_t ws_size, hipStream_t stream) {
  const float* enc = (const float*)d_in[0];
  const int* dur   = (const int*)d_in[1];
  const float* w1  = (const float*)d_in[2];
  const float* b1  = (const float*)d_in[3];
  const float* g1  = (const float*)d_in[4];
  const float* be1 = (const float*)d_in[5];
  const float* w2  = (const float*)d_in[6];
  const float* b2  = (const float*)d_in[7];
  const float* g2  = (const float*)d_in[8];
  const float* be2 = (const float*)d_in[9];
  const float* lw  = (const float*)d_in[10];
  const float* lb  = (const float*)d_in[11];

  float* out = (float*)d_out;
  float* expanded = out;                       // [B, L, D] = 67,108,864 f
  float* dpo = out + (long)BB * LL * DD;       // [B, T]

  // Scratch carved out of the 256 MB expanded region (gather writes it last).
  unsigned short* enc_pad = (unsigned short*)(expanded);              // 33.6 MB
  unsigned short* h1_pad  = (unsigned short*)(expanded + 9000000);    // 33.6 MB
  unsigned short* wt1     = (unsigned short*)(expanded + 18000000);   // 1.5 MB
  unsigned short* wt2     = (unsigned short*)(expanded + 18400000);   // 1.5 MB
  int* cum = (int*)d_ws;

  pad_convert_kernel<<<PAD_BLKS + 16, 256, 0, stream>>>(enc, enc_pad, h1_pad);
  convert_wt_kernel<<<dim3(DD / 64, KDIM / 64, 2), 256, 0, stream>>>(
      w1, wt1, w2, wt2);

  fused_conv_ln_kernel<1><<<ROWS / 128, 512, 0, stream>>>(
      enc_pad, wt1, b1, g1, be1, nullptr, nullptr, h1_pad, nullptr);
  fused_conv_ln_kernel<2><<<ROWS / 128, 512, 0, stream>>>(
      h1_pad, wt2, b2, g2, be2, lw, lb, nullptr, dpo);

  cumsum_kernel<<<BB, 1024, 0, stream>>>(dur, cum);
  gather_kernel<<<BB * LL, 128, 0, stream>>>(enc, cum, expanded);
}